// Round 5
// baseline (773.602 us; speedup 1.0000x reference)
//
#include <hip/hip_runtime.h>

#define NUM_USER 60000
#define NUM_ITEM 40000
#define NN 100000
#define NE 500000
#define DIM 64
#define KF 4
#define SCAN_CHUNK 512
#define NBLK_SCAN ((NN + 1 + SCAN_CHUNK - 1) / SCAN_CHUNK)

// sum within each 16-lane group of the wave (butterfly: all lanes get result)
__device__ __forceinline__ float red16(float v) {
    v += __shfl_xor(v, 1);
    v += __shfl_xor(v, 2);
    v += __shfl_xor(v, 4);
    v += __shfl_xor(v, 8);
    return v;
}

__device__ __forceinline__ float4 softmax4(float4 s) {
    float m = fmaxf(fmaxf(s.x, s.y), fmaxf(s.z, s.w));
    float e0 = expf(s.x - m), e1 = expf(s.y - m), e2 = expf(s.z - m), e3 = expf(s.w - m);
    float inv = 1.0f / (e0 + e1 + e2 + e3);
    return make_float4(e0 * inv, e1 * inv, e2 * inv, e3 * inv);
}

// wave per node: ego = concat(user,item); allemb = ego; T = tanh(l2n16(ego))
__global__ void k_init_tanh(const float* __restrict__ user, const float* __restrict__ item,
                            float* __restrict__ ego, float* __restrict__ allemb,
                            float* __restrict__ T) {
    int node = (blockIdx.x * blockDim.x + threadIdx.x) >> 6;
    int lane = threadIdx.x & 63;
    if (node >= NN) return;
    int i = node * DIM + lane;
    float v = (node < NUM_USER) ? user[i] : item[i - NUM_USER * DIM];
    ego[i] = v;
    allemb[i] = v;
    float ss = red16(v * v);
    T[i] = tanhf(v / fmaxf(sqrtf(ss), 1e-12f));
}

__global__ void k_count(const int* __restrict__ row0, const int* __restrict__ col0,
                        int* __restrict__ cnt) {
    int e = blockIdx.x * blockDim.x + threadIdx.x;
    if (e >= NE) return;
    atomicAdd(&cnt[row0[e]], 1);
    atomicAdd(&cnt[col0[e]], 1);
}

__global__ void k_dinv(const int* __restrict__ cnt, float* __restrict__ dinv) {
    int i = blockIdx.x * blockDim.x + threadIdx.x;
    if (i >= NN) return;
    int d = cnt[i];
    dinv[i] = (d > 0) ? rsqrtf((float)d) : 0.0f;
}

// --- 3-stage exclusive scan over cnt[NN] -> ptr[NN+1] ---
__global__ void k_scan1(const int* __restrict__ cnt, int* __restrict__ ptr,
                        int* __restrict__ bsum) {
    __shared__ int sm[SCAN_CHUNK];
    int tid = threadIdx.x;
    int idx = blockIdx.x * SCAN_CHUNK + tid;
    int x = (idx < NN) ? cnt[idx] : 0;
    sm[tid] = x;
    __syncthreads();
    for (int off = 1; off < SCAN_CHUNK; off <<= 1) {
        int v = (tid >= off) ? sm[tid - off] : 0;
        __syncthreads();
        sm[tid] += v;
        __syncthreads();
    }
    if (idx <= NN) ptr[idx] = sm[tid] - x;
    if (tid == SCAN_CHUNK - 1) bsum[blockIdx.x] = sm[tid];
}

__global__ void k_scan2(int* __restrict__ bsum, int* __restrict__ offs) {
    __shared__ int sm[256];
    int tid = threadIdx.x;
    int x = (tid < NBLK_SCAN) ? bsum[tid] : 0;
    sm[tid] = x;
    __syncthreads();
    for (int off = 1; off < 256; off <<= 1) {
        int v = (tid >= off) ? sm[tid - off] : 0;
        __syncthreads();
        sm[tid] += v;
        __syncthreads();
    }
    if (tid < NBLK_SCAN) offs[tid] = sm[tid] - x;
}

__global__ void k_scan3(int* __restrict__ ptr, const int* __restrict__ offs) {
    int idx = blockIdx.x * blockDim.x + threadIdx.x;
    if (idx <= NN) ptr[idx] += offs[idx / SCAN_CHUNK];
}

// build CSR. users are nodes [0,NUM_USER) so user-side slots are exactly [0,NE).
// renumbered edge id := user-side slot j1. eitem maps item slot -> edge id.
__global__ void k_fill(const int* __restrict__ row0, const int* __restrict__ col0,
                       int* __restrict__ pos, int* __restrict__ srcadj,
                       int* __restrict__ eitem, int* __restrict__ jpos1) {
    int e = blockIdx.x * blockDim.x + threadIdx.x;
    if (e >= NE) return;
    int r = row0[e], c = col0[e];
    int j1 = atomicAdd(&pos[r], 1);   // user-side slot (< NE): dst=r, src=c
    srcadj[j1] = c;
    jpos1[e] = j1;
    int j0 = atomicAdd(&pos[c], 1);   // item-side slot (>= NE): dst=c, src=r
    srcadj[j0] = r;
    eitem[j0 - NE] = j1;
}

// one pass: permute S into slot order, compute norm per slot, initial weights
__global__ void k_w0(const float* __restrict__ Sin, const int* __restrict__ row0,
                     const int* __restrict__ col0, const int* __restrict__ jpos1,
                     const float* __restrict__ dinv, float4* __restrict__ Scur4,
                     float* __restrict__ normu, float4* __restrict__ w0) {
    int e = blockIdx.x * blockDim.x + threadIdx.x;
    if (e >= NE) return;
    int j = jpos1[e];
    float n = dinv[row0[e]] * dinv[col0[e]];
    float4 s = make_float4(Sin[e], Sin[NE + e], Sin[2 * NE + e], Sin[3 * NE + e]);
    float4 p = softmax4(s);
    Scur4[j] = s;
    normu[j] = n;
    w0[j] = make_float4(n * p.x, n * p.y, n * p.z, n * p.w);
}

// Scur4 (slot order) -> Sout [4][E] original edge order
__global__ void k_sout(const float4* __restrict__ Scur4, const int* __restrict__ jpos1,
                       float* __restrict__ Sout) {
    int e = blockIdx.x * blockDim.x + threadIdx.x;
    if (e >= NE) return;
    float4 s = Scur4[jpos1[e]];
    Sout[e] = s.x;
    Sout[NE + e] = s.y;
    Sout[2 * NE + e] = s.z;
    Sout[3 * NE + e] = s.w;
}

// THE iteration kernel. wave per node.
// conv: acc = sum_j w[j] * ego[src_j]  (user: w sequential; item: w gather via eitem)
// score (user nodes): u = l2n16(acc); p_j = <u, T[c_j]>_16;
//   S[j] = softmax(S[j]) + p  (in place, own slots only)
//   wnext[j] = normu[j] * softmax(S_new[j])   (double-buffered vs wcur)
// flags: 1 = layer end (allemb += acc), 2 = write Twrite, 4 = final iteration
__global__ __launch_bounds__(256) void k_conv_score(
        const int* __restrict__ ptr, const int* __restrict__ srcadj,
        const int* __restrict__ eitem, const float* __restrict__ wcur,
        float* __restrict__ wnext, const float* __restrict__ normu,
        float* __restrict__ S4, const float* __restrict__ ego,
        const float* __restrict__ Tread, float* __restrict__ Twrite,
        float* __restrict__ xnew, float* __restrict__ allemb, int flags) {
    int node = (blockIdx.x * blockDim.x + threadIdx.x) >> 6;
    int lane = threadIdx.x & 63;
    if (node >= NN) return;
    int beg = ptr[node], end = ptr[node + 1];
    int k = lane >> 4;

    float a0 = 0.0f, a1 = 0.0f, a2 = 0.0f, a3 = 0.0f;
    int j = beg;
    if (node < NUM_USER) {
        for (; j + 4 <= end; j += 4) {
            int s0 = srcadj[j + 0], s1 = srcadj[j + 1];
            int s2 = srcadj[j + 2], s3 = srcadj[j + 3];
            float w0 = wcur[4 * j + k], w1 = wcur[4 * j + 4 + k];
            float w2 = wcur[4 * j + 8 + k], w3 = wcur[4 * j + 12 + k];
            a0 = fmaf(w0, ego[s0 * DIM + lane], a0);
            a1 = fmaf(w1, ego[s1 * DIM + lane], a1);
            a2 = fmaf(w2, ego[s2 * DIM + lane], a2);
            a3 = fmaf(w3, ego[s3 * DIM + lane], a3);
        }
        for (; j < end; ++j)
            a0 = fmaf(wcur[4 * j + k], ego[srcadj[j] * DIM + lane], a0);
    } else {
        for (; j + 4 <= end; j += 4) {
            int s0 = srcadj[j + 0], s1 = srcadj[j + 1];
            int s2 = srcadj[j + 2], s3 = srcadj[j + 3];
            int e0 = eitem[j - NE], e1 = eitem[j + 1 - NE];
            int e2 = eitem[j + 2 - NE], e3 = eitem[j + 3 - NE];
            float w0 = wcur[4 * e0 + k], w1 = wcur[4 * e1 + k];
            float w2 = wcur[4 * e2 + k], w3 = wcur[4 * e3 + k];
            a0 = fmaf(w0, ego[s0 * DIM + lane], a0);
            a1 = fmaf(w1, ego[s1 * DIM + lane], a1);
            a2 = fmaf(w2, ego[s2 * DIM + lane], a2);
            a3 = fmaf(w3, ego[s3 * DIM + lane], a3);
        }
        for (; j < end; ++j)
            a0 = fmaf(wcur[4 * eitem[j - NE] + k], ego[srcadj[j] * DIM + lane], a0);
    }
    float acc = (a0 + a1) + (a2 + a3);
    xnew[node * DIM + lane] = acc;

    if (flags & 1) {
        int i = node * DIM + lane;
        allemb[i] += acc;
        if (flags & 2) {
            float ss = red16(acc * acc);
            Twrite[i] = tanhf(acc / fmaxf(sqrtf(ss), 1e-12f));
        }
    }

    if (node >= NUM_USER) return;

    // ---- routing score + in-place S update + next-iteration weights ----
    float ssu = red16(acc * acc);
    float u = acc / fmaxf(sqrtf(ssu), 1e-12f);
    bool lead = (lane & 15) == 0;
    int last = flags & 4;
    for (j = beg; j < end; ++j) {
        int c = srcadj[j];
        float p = red16(u * Tread[c * DIM + lane]);       // all lanes get p_k
        float sk = S4[4 * j + k];                          // broadcast in group
        float m = fmaxf(sk, __shfl_xor(sk, 16));
        m = fmaxf(m, __shfl_xor(m, 32));
        float ex = expf(sk - m);
        float sum = ex + __shfl_xor(ex, 16);
        sum += __shfl_xor(sum, 32);
        float snew = ex / sum + p;
        float wv = 0.0f;
        if (!last) {
            float m2 = fmaxf(snew, __shfl_xor(snew, 16));
            m2 = fmaxf(m2, __shfl_xor(m2, 32));
            float ex2 = expf(snew - m2);
            float sum2 = ex2 + __shfl_xor(ex2, 16);
            sum2 += __shfl_xor(sum2, 32);
            wv = normu[j] * ex2 / sum2;
        }
        if (lead) {
            S4[4 * j + k] = snew;
            if (!last) wnext[4 * j + k] = wv;
        }
    }
}

extern "C" void kernel_launch(void* const* d_in, const int* in_sizes, int n_in,
                              void* d_out, int out_size, void* d_ws, size_t ws_size,
                              hipStream_t stream) {
    const float* user = (const float*)d_in[0];
    const float* item = (const float*)d_in[1];
    const float* S_in = (const float*)d_in[2];
    const int* edge = (const int*)d_in[3];
    const int* row0 = edge;
    const int* col0 = edge + NE;

    float* out = (float*)d_out;
    float* allemb = out;              // NN*DIM floats
    float* Sfinal = out + NN * DIM;   // KF*NE floats

    char* ws = (char*)d_ws;
    size_t off = 0;
    auto carve = [&](size_t bytes) { void* p = ws + off; off += (bytes + 255) & ~(size_t)255; return p; };
    int* cnt = (int*)carve((NN + 1) * sizeof(int));
    int* ptr = (int*)carve((NN + 1) * sizeof(int));
    int* pos = (int*)carve((NN + 1) * sizeof(int));
    int* bsum = (int*)carve(256 * sizeof(int));
    int* offs = (int*)carve(256 * sizeof(int));
    int* srcadj = (int*)carve((size_t)2 * NE * sizeof(int));
    int* eitem = (int*)carve((size_t)NE * sizeof(int));
    int* jpos1 = (int*)carve((size_t)NE * sizeof(int));
    float* dinv = (float*)carve(NN * sizeof(float));
    float* normu = (float*)carve((size_t)NE * sizeof(float));
    float4* Scur4 = (float4*)carve((size_t)NE * sizeof(float4));
    float4* wA = (float4*)carve((size_t)NE * sizeof(float4));
    float4* wB = (float4*)carve((size_t)NE * sizeof(float4));
    float* egoA = (float*)carve((size_t)NN * DIM * sizeof(float));
    float* egoB = (float*)carve((size_t)NN * DIM * sizeof(float));
    float* TA = (float*)carve((size_t)NN * DIM * sizeof(float));
    float* TB = (float*)carve((size_t)NN * DIM * sizeof(float));

    hipMemsetAsync(cnt, 0, (NN + 1) * sizeof(int), stream);

    k_count<<<(NE + 255) / 256, 256, 0, stream>>>(row0, col0, cnt);
    k_dinv<<<(NN + 255) / 256, 256, 0, stream>>>(cnt, dinv);
    k_scan1<<<NBLK_SCAN, SCAN_CHUNK, 0, stream>>>(cnt, ptr, bsum);
    k_scan2<<<1, 256, 0, stream>>>(bsum, offs);
    k_scan3<<<(NN + 1 + 255) / 256, 256, 0, stream>>>(ptr, offs);
    hipMemcpyAsync(pos, ptr, (NN + 1) * sizeof(int), hipMemcpyDeviceToDevice, stream);
    k_fill<<<(NE + 255) / 256, 256, 0, stream>>>(row0, col0, pos, srcadj, eitem, jpos1);
    k_w0<<<(NE + 255) / 256, 256, 0, stream>>>(S_in, row0, col0, jpos1, dinv,
                                               Scur4, normu, wA);
    k_init_tanh<<<(NN * 64 + 255) / 256, 256, 0, stream>>>(user, item, egoA, allemb, TA);

    float* ego = egoA;
    float* xn = egoB;
    float* Trd = TA;
    float* Twr = TB;
    float4* wcur = wA;
    float4* wnx = wB;
    for (int layer = 0; layer < 2; ++layer) {
        for (int it = 0; it < 2; ++it) {
            int flags = 0;
            if (it == 1) flags |= 1;                  // layer end: allemb += acc
            if (it == 1 && layer == 0) flags |= 2;    // write T for next layer
            if (layer == 1 && it == 1) flags |= 4;    // final: skip wnext
            k_conv_score<<<(NN * 64 + 255) / 256, 256, 0, stream>>>(
                ptr, srcadj, eitem, (const float*)wcur, (float*)wnx, normu,
                (float*)Scur4, ego, Trd, Twr, xn, allemb, flags);
            float4* tw = wcur; wcur = wnx; wnx = tw;
        }
        float* t = ego; ego = xn; xn = t;
        t = Trd; Trd = Twr; Twr = t;
    }
    k_sout<<<(NE + 255) / 256, 256, 0, stream>>>(Scur4, jpos1, Sfinal);
}

// Round 6
// 640.420 us; speedup vs baseline: 1.2080x; 1.2080x over previous
//
#include <hip/hip_runtime.h>

#define NUM_USER 60000
#define NUM_ITEM 40000
#define NN 100000
#define NE 500000
#define DIM 64
#define KF 4
#define SCAN_CHUNK 512
#define NBLK_SCAN ((NN + 1 + SCAN_CHUNK - 1) / SCAN_CHUNK)

// sum within each 16-lane group of the wave (butterfly: all lanes get result)
__device__ __forceinline__ float red16(float v) {
    v += __shfl_xor(v, 1);
    v += __shfl_xor(v, 2);
    v += __shfl_xor(v, 4);
    v += __shfl_xor(v, 8);
    return v;
}

__device__ __forceinline__ float4 softmax4(float4 s) {
    float m = fmaxf(fmaxf(s.x, s.y), fmaxf(s.z, s.w));
    float e0 = expf(s.x - m), e1 = expf(s.y - m), e2 = expf(s.z - m), e3 = expf(s.w - m);
    float inv = 1.0f / (e0 + e1 + e2 + e3);
    return make_float4(e0 * inv, e1 * inv, e2 * inv, e3 * inv);
}

// wave per node: ego = concat(user,item); allemb = ego; T = tanh(l2n16(ego))
__global__ void k_init_tanh(const float* __restrict__ user, const float* __restrict__ item,
                            float* __restrict__ ego, float* __restrict__ allemb,
                            float* __restrict__ T) {
    int node = (blockIdx.x * blockDim.x + threadIdx.x) >> 6;
    int lane = threadIdx.x & 63;
    if (node >= NN) return;
    int i = node * DIM + lane;
    float v = (node < NUM_USER) ? user[i] : item[i - NUM_USER * DIM];
    ego[i] = v;
    allemb[i] = v;
    float ss = red16(v * v);
    T[i] = tanhf(v / fmaxf(sqrtf(ss), 1e-12f));
}

__global__ void k_count(const int* __restrict__ row0, const int* __restrict__ col0,
                        int* __restrict__ cnt) {
    int e = blockIdx.x * blockDim.x + threadIdx.x;
    if (e >= NE) return;
    atomicAdd(&cnt[row0[e]], 1);
    atomicAdd(&cnt[col0[e]], 1);
}

__global__ void k_dinv(const int* __restrict__ cnt, float* __restrict__ dinv) {
    int i = blockIdx.x * blockDim.x + threadIdx.x;
    if (i >= NN) return;
    int d = cnt[i];
    dinv[i] = (d > 0) ? rsqrtf((float)d) : 0.0f;
}

// --- 3-stage exclusive scan over cnt[NN] -> ptr[NN+1] ---
__global__ void k_scan1(const int* __restrict__ cnt, int* __restrict__ ptr,
                        int* __restrict__ bsum) {
    __shared__ int sm[SCAN_CHUNK];
    int tid = threadIdx.x;
    int idx = blockIdx.x * SCAN_CHUNK + tid;
    int x = (idx < NN) ? cnt[idx] : 0;
    sm[tid] = x;
    __syncthreads();
    for (int off = 1; off < SCAN_CHUNK; off <<= 1) {
        int v = (tid >= off) ? sm[tid - off] : 0;
        __syncthreads();
        sm[tid] += v;
        __syncthreads();
    }
    if (idx <= NN) ptr[idx] = sm[tid] - x;
    if (tid == SCAN_CHUNK - 1) bsum[blockIdx.x] = sm[tid];
}

__global__ void k_scan2(int* __restrict__ bsum, int* __restrict__ offs) {
    __shared__ int sm[256];
    int tid = threadIdx.x;
    int x = (tid < NBLK_SCAN) ? bsum[tid] : 0;
    sm[tid] = x;
    __syncthreads();
    for (int off = 1; off < 256; off <<= 1) {
        int v = (tid >= off) ? sm[tid - off] : 0;
        __syncthreads();
        sm[tid] += v;
        __syncthreads();
    }
    if (tid < NBLK_SCAN) offs[tid] = sm[tid] - x;
}

__global__ void k_scan3(int* __restrict__ ptr, const int* __restrict__ offs) {
    int idx = blockIdx.x * blockDim.x + threadIdx.x;
    if (idx <= NN) ptr[idx] += offs[idx / SCAN_CHUNK];
}

// build CSR. users are nodes [0,NUM_USER) so user-side slots are exactly [0,NE).
// renumbered edge id := user-side slot j1. eitem maps item slot -> edge id.
__global__ void k_fill(const int* __restrict__ row0, const int* __restrict__ col0,
                       int* __restrict__ pos, int* __restrict__ srcadj,
                       int* __restrict__ eitem, int* __restrict__ jpos1) {
    int e = blockIdx.x * blockDim.x + threadIdx.x;
    if (e >= NE) return;
    int r = row0[e], c = col0[e];
    int j1 = atomicAdd(&pos[r], 1);   // user-side slot (< NE): dst=r, src=c
    srcadj[j1] = c;
    jpos1[e] = j1;
    int j0 = atomicAdd(&pos[c], 1);   // item-side slot (>= NE): dst=c, src=r
    srcadj[j0] = r;
    eitem[j0 - NE] = j1;
}

// one pass: permute S into slot order, compute norm per slot, initial weights
__global__ void k_w0(const float* __restrict__ Sin, const int* __restrict__ row0,
                     const int* __restrict__ col0, const int* __restrict__ jpos1,
                     const float* __restrict__ dinv, float4* __restrict__ Scur4,
                     float* __restrict__ normu, float4* __restrict__ w0) {
    int e = blockIdx.x * blockDim.x + threadIdx.x;
    if (e >= NE) return;
    int j = jpos1[e];
    float n = dinv[row0[e]] * dinv[col0[e]];
    float4 s = make_float4(Sin[e], Sin[NE + e], Sin[2 * NE + e], Sin[3 * NE + e]);
    float4 p = softmax4(s);
    Scur4[j] = s;
    normu[j] = n;
    w0[j] = make_float4(n * p.x, n * p.y, n * p.z, n * p.w);
}

// Scur4 (slot order) -> Sout [4][E] original edge order
__global__ void k_sout(const float4* __restrict__ Scur4, const int* __restrict__ jpos1,
                       float* __restrict__ Sout) {
    int e = blockIdx.x * blockDim.x + threadIdx.x;
    if (e >= NE) return;
    float4 s = Scur4[jpos1[e]];
    Sout[e] = s.x;
    Sout[NE + e] = s.y;
    Sout[2 * NE + e] = s.z;
    Sout[3 * NE + e] = s.w;
}

// fused gather conv + routing score. wave per node.
// conv: acc = sum_j w[j]*ego[src_j]  (user: w sequential; item: w gathered via eitem)
// score (user nodes): u = l2n16(acc); pscore[j] = <u, T[src_j]>_16 (sequential float4)
// flags: 1 = layer end (allemb += acc), 2 = also write Twrite
__global__ __launch_bounds__(256) void k_conv_score(
        const int* __restrict__ ptr, const int* __restrict__ srcadj,
        const int* __restrict__ eitem, const float* __restrict__ wcur,
        float* __restrict__ pscore, const float* __restrict__ ego,
        const float* __restrict__ Tread, float* __restrict__ Twrite,
        float* __restrict__ xnew, float* __restrict__ allemb, int flags) {
    int node = (blockIdx.x * blockDim.x + threadIdx.x) >> 6;
    int lane = threadIdx.x & 63;
    if (node >= NN) return;
    int beg = ptr[node], end = ptr[node + 1];
    int k = lane >> 4;

    float a0 = 0.0f, a1 = 0.0f, a2 = 0.0f, a3 = 0.0f;
    int j = beg;
    if (node < NUM_USER) {
        for (; j + 4 <= end; j += 4) {
            int s0 = srcadj[j + 0], s1 = srcadj[j + 1];
            int s2 = srcadj[j + 2], s3 = srcadj[j + 3];
            float w0 = wcur[4 * j + k], w1 = wcur[4 * j + 4 + k];
            float w2 = wcur[4 * j + 8 + k], w3 = wcur[4 * j + 12 + k];
            a0 = fmaf(w0, ego[s0 * DIM + lane], a0);
            a1 = fmaf(w1, ego[s1 * DIM + lane], a1);
            a2 = fmaf(w2, ego[s2 * DIM + lane], a2);
            a3 = fmaf(w3, ego[s3 * DIM + lane], a3);
        }
        for (; j < end; ++j)
            a0 = fmaf(wcur[4 * j + k], ego[srcadj[j] * DIM + lane], a0);
    } else {
        for (; j + 4 <= end; j += 4) {
            int s0 = srcadj[j + 0], s1 = srcadj[j + 1];
            int s2 = srcadj[j + 2], s3 = srcadj[j + 3];
            int e0 = eitem[j - NE], e1 = eitem[j + 1 - NE];
            int e2 = eitem[j + 2 - NE], e3 = eitem[j + 3 - NE];
            float w0 = wcur[4 * e0 + k], w1 = wcur[4 * e1 + k];
            float w2 = wcur[4 * e2 + k], w3 = wcur[4 * e3 + k];
            a0 = fmaf(w0, ego[s0 * DIM + lane], a0);
            a1 = fmaf(w1, ego[s1 * DIM + lane], a1);
            a2 = fmaf(w2, ego[s2 * DIM + lane], a2);
            a3 = fmaf(w3, ego[s3 * DIM + lane], a3);
        }
        for (; j < end; ++j)
            a0 = fmaf(wcur[4 * eitem[j - NE] + k], ego[srcadj[j] * DIM + lane], a0);
    }
    float acc = (a0 + a1) + (a2 + a3);
    xnew[node * DIM + lane] = acc;

    if (flags & 1) {
        int i = node * DIM + lane;
        allemb[i] += acc;
        if (flags & 2) {
            float ss = red16(acc * acc);
            Twrite[i] = tanhf(acc / fmaxf(sqrtf(ss), 1e-12f));
        }
    }

    if (node >= NUM_USER) return;

    // ---- routing score: pscore[4*j+k] = <u, T[c_j]>_16 ----
    float ssu = red16(acc * acc);
    float u = acc / fmaxf(sqrtf(ssu), 1e-12f);
    bool lead = (lane & 15) == 0;
    j = beg;
    for (; j + 2 <= end; j += 2) {
        int s0 = srcadj[j], s1 = srcadj[j + 1];
        float t0 = Tread[s0 * DIM + lane];
        float t1 = Tread[s1 * DIM + lane];
        float p0 = red16(u * t0);
        float p1 = red16(u * t1);
        if (lead) {
            pscore[4 * j + k] = p0;
            pscore[4 * (j + 1) + k] = p1;
        }
    }
    for (; j < end; ++j) {
        float p = red16(u * Tread[srcadj[j] * DIM + lane]);
        if (lead) pscore[4 * j + k] = p;
    }
}

// thread per edge slot, all sequential float4:
// snew = softmax4(S4) + pscore; S4 = snew; if !last: w = normu * softmax4(snew)
__global__ void k_supd(float4* __restrict__ S4, const float4* __restrict__ pscore,
                       const float* __restrict__ normu, float4* __restrict__ w,
                       int last) {
    int j = blockIdx.x * blockDim.x + threadIdx.x;
    if (j >= NE) return;
    float4 s = softmax4(S4[j]);
    float4 p = pscore[j];
    float4 snew = make_float4(s.x + p.x, s.y + p.y, s.z + p.z, s.w + p.w);
    S4[j] = snew;
    if (!last) {
        float4 q = softmax4(snew);
        float n = normu[j];
        w[j] = make_float4(n * q.x, n * q.y, n * q.z, n * q.w);
    }
}

extern "C" void kernel_launch(void* const* d_in, const int* in_sizes, int n_in,
                              void* d_out, int out_size, void* d_ws, size_t ws_size,
                              hipStream_t stream) {
    const float* user = (const float*)d_in[0];
    const float* item = (const float*)d_in[1];
    const float* S_in = (const float*)d_in[2];
    const int* edge = (const int*)d_in[3];
    const int* row0 = edge;
    const int* col0 = edge + NE;

    float* out = (float*)d_out;
    float* allemb = out;              // NN*DIM floats
    float* Sfinal = out + NN * DIM;   // KF*NE floats

    char* ws = (char*)d_ws;
    size_t off = 0;
    auto carve = [&](size_t bytes) { void* p = ws + off; off += (bytes + 255) & ~(size_t)255; return p; };
    int* cnt = (int*)carve((NN + 1) * sizeof(int));
    int* ptr = (int*)carve((NN + 1) * sizeof(int));
    int* pos = (int*)carve((NN + 1) * sizeof(int));
    int* bsum = (int*)carve(256 * sizeof(int));
    int* offs = (int*)carve(256 * sizeof(int));
    int* srcadj = (int*)carve((size_t)2 * NE * sizeof(int));
    int* eitem = (int*)carve((size_t)NE * sizeof(int));
    int* jpos1 = (int*)carve((size_t)NE * sizeof(int));
    float* dinv = (float*)carve(NN * sizeof(float));
    float* normu = (float*)carve((size_t)NE * sizeof(float));
    float4* Scur4 = (float4*)carve((size_t)NE * sizeof(float4));
    float4* wbuf = (float4*)carve((size_t)NE * sizeof(float4));
    float4* pscore = (float4*)carve((size_t)NE * sizeof(float4));
    float* egoA = (float*)carve((size_t)NN * DIM * sizeof(float));
    float* egoB = (float*)carve((size_t)NN * DIM * sizeof(float));
    float* TA = (float*)carve((size_t)NN * DIM * sizeof(float));
    float* TB = (float*)carve((size_t)NN * DIM * sizeof(float));

    hipMemsetAsync(cnt, 0, (NN + 1) * sizeof(int), stream);

    k_count<<<(NE + 255) / 256, 256, 0, stream>>>(row0, col0, cnt);
    k_dinv<<<(NN + 255) / 256, 256, 0, stream>>>(cnt, dinv);
    k_scan1<<<NBLK_SCAN, SCAN_CHUNK, 0, stream>>>(cnt, ptr, bsum);
    k_scan2<<<1, 256, 0, stream>>>(bsum, offs);
    k_scan3<<<(NN + 1 + 255) / 256, 256, 0, stream>>>(ptr, offs);
    hipMemcpyAsync(pos, ptr, (NN + 1) * sizeof(int), hipMemcpyDeviceToDevice, stream);
    k_fill<<<(NE + 255) / 256, 256, 0, stream>>>(row0, col0, pos, srcadj, eitem, jpos1);
    k_w0<<<(NE + 255) / 256, 256, 0, stream>>>(S_in, row0, col0, jpos1, dinv,
                                               Scur4, normu, wbuf);
    k_init_tanh<<<(NN * 64 + 255) / 256, 256, 0, stream>>>(user, item, egoA, allemb, TA);

    float* ego = egoA;
    float* xn = egoB;
    float* Trd = TA;
    float* Twr = TB;
    for (int layer = 0; layer < 2; ++layer) {
        for (int it = 0; it < 2; ++it) {
            int flags = 0;
            if (it == 1) flags |= 1;                  // layer end: allemb += acc
            if (it == 1 && layer == 0) flags |= 2;    // write T for next layer
            k_conv_score<<<(NN * 64 + 255) / 256, 256, 0, stream>>>(
                ptr, srcadj, eitem, (const float*)wbuf, (float*)pscore,
                ego, Trd, Twr, xn, allemb, flags);
            int last = (layer == 1 && it == 1) ? 1 : 0;
            k_supd<<<(NE + 255) / 256, 256, 0, stream>>>(Scur4, pscore, normu, wbuf, last);
        }
        float* t = ego; ego = xn; xn = t;
        t = Trd; Trd = Twr; Twr = t;
    }
    k_sout<<<(NE + 255) / 256, 256, 0, stream>>>(Scur4, jpos1, Sfinal);
}

// Round 7
// 604.770 us; speedup vs baseline: 1.2792x; 1.0589x over previous
//
#include <hip/hip_runtime.h>
#include <hip/hip_bf16.h>

#define NUM_USER 60000
#define NUM_ITEM 40000
#define NN 100000
#define NE 500000
#define DIM 64
#define KF 4
#define SCAN_CHUNK 512
#define NBLK_SCAN ((NN + 1 + SCAN_CHUNK - 1) / SCAN_CHUNK)

typedef __hip_bfloat16 bf16;

// sum within each 16-lane group of the wave (butterfly: all lanes get result)
__device__ __forceinline__ float red16(float v) {
    v += __shfl_xor(v, 1);
    v += __shfl_xor(v, 2);
    v += __shfl_xor(v, 4);
    v += __shfl_xor(v, 8);
    return v;
}

__device__ __forceinline__ float4 softmax4(float4 s) {
    float m = fmaxf(fmaxf(s.x, s.y), fmaxf(s.z, s.w));
    float e0 = expf(s.x - m), e1 = expf(s.y - m), e2 = expf(s.z - m), e3 = expf(s.w - m);
    float inv = 1.0f / (e0 + e1 + e2 + e3);
    return make_float4(e0 * inv, e1 * inv, e2 * inv, e3 * inv);
}

// wave per node: ego(bf16) = concat(user,item); allemb(fp32) = exact input;
// T(bf16) = tanh(l2n16(input))
__global__ void k_init_tanh(const float* __restrict__ user, const float* __restrict__ item,
                            bf16* __restrict__ ego, float* __restrict__ allemb,
                            bf16* __restrict__ T) {
    int node = (blockIdx.x * blockDim.x + threadIdx.x) >> 6;
    int lane = threadIdx.x & 63;
    if (node >= NN) return;
    int i = node * DIM + lane;
    float v = (node < NUM_USER) ? user[i] : item[i - NUM_USER * DIM];
    ego[i] = __float2bfloat16(v);
    allemb[i] = v;
    float ss = red16(v * v);
    T[i] = __float2bfloat16(tanhf(v / fmaxf(sqrtf(ss), 1e-12f)));
}

__global__ void k_count(const int* __restrict__ row0, const int* __restrict__ col0,
                        int* __restrict__ cnt) {
    int e = blockIdx.x * blockDim.x + threadIdx.x;
    if (e >= NE) return;
    atomicAdd(&cnt[row0[e]], 1);
    atomicAdd(&cnt[col0[e]], 1);
}

__global__ void k_dinv(const int* __restrict__ cnt, float* __restrict__ dinv) {
    int i = blockIdx.x * blockDim.x + threadIdx.x;
    if (i >= NN) return;
    int d = cnt[i];
    dinv[i] = (d > 0) ? rsqrtf((float)d) : 0.0f;
}

// --- 3-stage exclusive scan over cnt[NN] -> ptr[NN+1] ---
__global__ void k_scan1(const int* __restrict__ cnt, int* __restrict__ ptr,
                        int* __restrict__ bsum) {
    __shared__ int sm[SCAN_CHUNK];
    int tid = threadIdx.x;
    int idx = blockIdx.x * SCAN_CHUNK + tid;
    int x = (idx < NN) ? cnt[idx] : 0;
    sm[tid] = x;
    __syncthreads();
    for (int off = 1; off < SCAN_CHUNK; off <<= 1) {
        int v = (tid >= off) ? sm[tid - off] : 0;
        __syncthreads();
        sm[tid] += v;
        __syncthreads();
    }
    if (idx <= NN) ptr[idx] = sm[tid] - x;
    if (tid == SCAN_CHUNK - 1) bsum[blockIdx.x] = sm[tid];
}

__global__ void k_scan2(int* __restrict__ bsum, int* __restrict__ offs) {
    __shared__ int sm[256];
    int tid = threadIdx.x;
    int x = (tid < NBLK_SCAN) ? bsum[tid] : 0;
    sm[tid] = x;
    __syncthreads();
    for (int off = 1; off < 256; off <<= 1) {
        int v = (tid >= off) ? sm[tid - off] : 0;
        __syncthreads();
        sm[tid] += v;
        __syncthreads();
    }
    if (tid < NBLK_SCAN) offs[tid] = sm[tid] - x;
}

__global__ void k_scan3(int* __restrict__ ptr, const int* __restrict__ offs) {
    int idx = blockIdx.x * blockDim.x + threadIdx.x;
    if (idx <= NN) ptr[idx] += offs[idx / SCAN_CHUNK];
}

// build CSR. users are nodes [0,NUM_USER) so user-side slots are exactly [0,NE).
// renumbered edge id := user-side slot j1. eitem maps item slot -> edge id.
__global__ void k_fill(const int* __restrict__ row0, const int* __restrict__ col0,
                       int* __restrict__ pos, int* __restrict__ srcadj,
                       int* __restrict__ eitem, int* __restrict__ jpos1) {
    int e = blockIdx.x * blockDim.x + threadIdx.x;
    if (e >= NE) return;
    int r = row0[e], c = col0[e];
    int j1 = atomicAdd(&pos[r], 1);   // user-side slot (< NE): dst=r, src=c
    srcadj[j1] = c;
    jpos1[e] = j1;
    int j0 = atomicAdd(&pos[c], 1);   // item-side slot (>= NE): dst=c, src=r
    srcadj[j0] = r;
    eitem[j0 - NE] = j1;
}

// one pass: permute S into slot order, compute norm per slot, initial weights
__global__ void k_w0(const float* __restrict__ Sin, const int* __restrict__ row0,
                     const int* __restrict__ col0, const int* __restrict__ jpos1,
                     const float* __restrict__ dinv, float4* __restrict__ Scur4,
                     float* __restrict__ normu, float4* __restrict__ w0) {
    int e = blockIdx.x * blockDim.x + threadIdx.x;
    if (e >= NE) return;
    int j = jpos1[e];
    float n = dinv[row0[e]] * dinv[col0[e]];
    float4 s = make_float4(Sin[e], Sin[NE + e], Sin[2 * NE + e], Sin[3 * NE + e]);
    float4 p = softmax4(s);
    Scur4[j] = s;
    normu[j] = n;
    w0[j] = make_float4(n * p.x, n * p.y, n * p.z, n * p.w);
}

// Scur4 (slot order) -> Sout [4][E] original edge order
__global__ void k_sout(const float4* __restrict__ Scur4, const int* __restrict__ jpos1,
                       float* __restrict__ Sout) {
    int e = blockIdx.x * blockDim.x + threadIdx.x;
    if (e >= NE) return;
    float4 s = Scur4[jpos1[e]];
    Sout[e] = s.x;
    Sout[NE + e] = s.y;
    Sout[2 * NE + e] = s.z;
    Sout[3 * NE + e] = s.w;
}

// fused gather conv + routing score. wave per node. ego/T are bf16 rows (128 B).
// conv: acc = sum_j w[j]*ego[src_j]  (user: w sequential; item: w gathered via eitem)
// score (user nodes): u = l2n16(acc); pscore[j] = <u, T[src_j]>_16 (sequential float4)
// flags: 1 = layer end (allemb += acc), 2 = write Twrite, 4 = write xnext (next ego)
__global__ __launch_bounds__(256) void k_conv_score(
        const int* __restrict__ ptr, const int* __restrict__ srcadj,
        const int* __restrict__ eitem, const float* __restrict__ wcur,
        float* __restrict__ pscore, const bf16* __restrict__ ego,
        const bf16* __restrict__ Tread, bf16* __restrict__ Twrite,
        bf16* __restrict__ xnext, float* __restrict__ allemb, int flags) {
    int node = (blockIdx.x * blockDim.x + threadIdx.x) >> 6;
    int lane = threadIdx.x & 63;
    if (node >= NN) return;
    int beg = ptr[node], end = ptr[node + 1];
    int k = lane >> 4;

    float a0 = 0.0f, a1 = 0.0f, a2 = 0.0f, a3 = 0.0f;
    int j = beg;
    if (node < NUM_USER) {
        for (; j + 4 <= end; j += 4) {
            int s0 = srcadj[j + 0], s1 = srcadj[j + 1];
            int s2 = srcadj[j + 2], s3 = srcadj[j + 3];
            float w0 = wcur[4 * j + k], w1 = wcur[4 * j + 4 + k];
            float w2 = wcur[4 * j + 8 + k], w3 = wcur[4 * j + 12 + k];
            a0 = fmaf(w0, __bfloat162float(ego[s0 * DIM + lane]), a0);
            a1 = fmaf(w1, __bfloat162float(ego[s1 * DIM + lane]), a1);
            a2 = fmaf(w2, __bfloat162float(ego[s2 * DIM + lane]), a2);
            a3 = fmaf(w3, __bfloat162float(ego[s3 * DIM + lane]), a3);
        }
        for (; j < end; ++j)
            a0 = fmaf(wcur[4 * j + k], __bfloat162float(ego[srcadj[j] * DIM + lane]), a0);
    } else {
        for (; j + 4 <= end; j += 4) {
            int s0 = srcadj[j + 0], s1 = srcadj[j + 1];
            int s2 = srcadj[j + 2], s3 = srcadj[j + 3];
            int e0 = eitem[j - NE], e1 = eitem[j + 1 - NE];
            int e2 = eitem[j + 2 - NE], e3 = eitem[j + 3 - NE];
            float w0 = wcur[4 * e0 + k], w1 = wcur[4 * e1 + k];
            float w2 = wcur[4 * e2 + k], w3 = wcur[4 * e3 + k];
            a0 = fmaf(w0, __bfloat162float(ego[s0 * DIM + lane]), a0);
            a1 = fmaf(w1, __bfloat162float(ego[s1 * DIM + lane]), a1);
            a2 = fmaf(w2, __bfloat162float(ego[s2 * DIM + lane]), a2);
            a3 = fmaf(w3, __bfloat162float(ego[s3 * DIM + lane]), a3);
        }
        for (; j < end; ++j)
            a0 = fmaf(wcur[4 * eitem[j - NE] + k],
                      __bfloat162float(ego[srcadj[j] * DIM + lane]), a0);
    }
    float acc = (a0 + a1) + (a2 + a3);

    if (flags & 1) {
        int i = node * DIM + lane;
        allemb[i] += acc;
        if (flags & 4) xnext[i] = __float2bfloat16(acc);
        if (flags & 2) {
            float ss = red16(acc * acc);
            Twrite[i] = __float2bfloat16(tanhf(acc / fmaxf(sqrtf(ss), 1e-12f)));
        }
    }

    if (node >= NUM_USER) return;

    // ---- routing score: pscore[4*j+k] = <u, T[c_j]>_16 ----
    float ssu = red16(acc * acc);
    float u = acc / fmaxf(sqrtf(ssu), 1e-12f);
    bool lead = (lane & 15) == 0;
    j = beg;
    for (; j + 2 <= end; j += 2) {
        int s0 = srcadj[j], s1 = srcadj[j + 1];
        float t0 = __bfloat162float(Tread[s0 * DIM + lane]);
        float t1 = __bfloat162float(Tread[s1 * DIM + lane]);
        float p0 = red16(u * t0);
        float p1 = red16(u * t1);
        if (lead) {
            pscore[4 * j + k] = p0;
            pscore[4 * (j + 1) + k] = p1;
        }
    }
    for (; j < end; ++j) {
        float p = red16(u * __bfloat162float(Tread[srcadj[j] * DIM + lane]));
        if (lead) pscore[4 * j + k] = p;
    }
}

// thread per edge slot, all sequential float4:
// snew = softmax4(S4) + pscore; S4 = snew; if !last: w = normu * softmax4(snew)
__global__ void k_supd(float4* __restrict__ S4, const float4* __restrict__ pscore,
                       const float* __restrict__ normu, float4* __restrict__ w,
                       int last) {
    int j = blockIdx.x * blockDim.x + threadIdx.x;
    if (j >= NE) return;
    float4 s = softmax4(S4[j]);
    float4 p = pscore[j];
    float4 snew = make_float4(s.x + p.x, s.y + p.y, s.z + p.z, s.w + p.w);
    S4[j] = snew;
    if (!last) {
        float4 q = softmax4(snew);
        float n = normu[j];
        w[j] = make_float4(n * q.x, n * q.y, n * q.z, n * q.w);
    }
}

extern "C" void kernel_launch(void* const* d_in, const int* in_sizes, int n_in,
                              void* d_out, int out_size, void* d_ws, size_t ws_size,
                              hipStream_t stream) {
    const float* user = (const float*)d_in[0];
    const float* item = (const float*)d_in[1];
    const float* S_in = (const float*)d_in[2];
    const int* edge = (const int*)d_in[3];
    const int* row0 = edge;
    const int* col0 = edge + NE;

    float* out = (float*)d_out;
    float* allemb = out;              // NN*DIM floats
    float* Sfinal = out + NN * DIM;   // KF*NE floats

    char* ws = (char*)d_ws;
    size_t off = 0;
    auto carve = [&](size_t bytes) { void* p = ws + off; off += (bytes + 255) & ~(size_t)255; return p; };
    int* cnt = (int*)carve((NN + 1) * sizeof(int));
    int* ptr = (int*)carve((NN + 1) * sizeof(int));
    int* pos = (int*)carve((NN + 1) * sizeof(int));
    int* bsum = (int*)carve(256 * sizeof(int));
    int* offs = (int*)carve(256 * sizeof(int));
    int* srcadj = (int*)carve((size_t)2 * NE * sizeof(int));
    int* eitem = (int*)carve((size_t)NE * sizeof(int));
    int* jpos1 = (int*)carve((size_t)NE * sizeof(int));
    float* dinv = (float*)carve(NN * sizeof(float));
    float* normu = (float*)carve((size_t)NE * sizeof(float));
    float4* Scur4 = (float4*)carve((size_t)NE * sizeof(float4));
    float4* wbuf = (float4*)carve((size_t)NE * sizeof(float4));
    float4* pscore = (float4*)carve((size_t)NE * sizeof(float4));
    bf16* egoA = (bf16*)carve((size_t)NN * DIM * sizeof(bf16));
    bf16* egoB = (bf16*)carve((size_t)NN * DIM * sizeof(bf16));
    bf16* TA = (bf16*)carve((size_t)NN * DIM * sizeof(bf16));
    bf16* TB = (bf16*)carve((size_t)NN * DIM * sizeof(bf16));

    hipMemsetAsync(cnt, 0, (NN + 1) * sizeof(int), stream);

    k_count<<<(NE + 255) / 256, 256, 0, stream>>>(row0, col0, cnt);
    k_dinv<<<(NN + 255) / 256, 256, 0, stream>>>(cnt, dinv);
    k_scan1<<<NBLK_SCAN, SCAN_CHUNK, 0, stream>>>(cnt, ptr, bsum);
    k_scan2<<<1, 256, 0, stream>>>(bsum, offs);
    k_scan3<<<(NN + 1 + 255) / 256, 256, 0, stream>>>(ptr, offs);
    hipMemcpyAsync(pos, ptr, (NN + 1) * sizeof(int), hipMemcpyDeviceToDevice, stream);
    k_fill<<<(NE + 255) / 256, 256, 0, stream>>>(row0, col0, pos, srcadj, eitem, jpos1);
    k_w0<<<(NE + 255) / 256, 256, 0, stream>>>(S_in, row0, col0, jpos1, dinv,
                                               Scur4, normu, wbuf);
    k_init_tanh<<<(NN * 64 + 255) / 256, 256, 0, stream>>>(user, item, egoA, allemb, TA);

    bf16* ego = egoA;
    bf16* xn = egoB;
    bf16* Trd = TA;
    bf16* Twr = TB;
    for (int layer = 0; layer < 2; ++layer) {
        for (int it = 0; it < 2; ++it) {
            int flags = 0;
            if (it == 1) flags |= 1;                  // layer end: allemb += acc
            if (it == 1 && layer == 0) flags |= 2 | 4; // write T + next ego
            k_conv_score<<<(NN * 64 + 255) / 256, 256, 0, stream>>>(
                ptr, srcadj, eitem, (const float*)wbuf, (float*)pscore,
                ego, Trd, Twr, xn, allemb, flags);
            int last = (layer == 1 && it == 1) ? 1 : 0;
            k_supd<<<(NE + 255) / 256, 256, 0, stream>>>(Scur4, pscore, normu, wbuf, last);
        }
        bf16* t = ego; ego = xn; xn = t;
        t = Trd; Trd = Twr; Twr = t;
    }
    k_sout<<<(NE + 255) / 256, 256, 0, stream>>>(Scur4, jpos1, Sfinal);
}